// Round 11
// baseline (798.442 us; speedup 1.0000x reference)
//
#include <hip/hip_runtime.h>

#define N_NODES 100000
#define N_EDGES 1600000
#define D 64
#define N_GRAPHS 64
#define NBLK ((N_NODES + 255) / 256)   // 391 scan blocks
#define WTS 68                         // WT row stride (floats): conflict-free
#define NS8 (N_NODES * 8)              // floats per feature-slice

// ---------------- init: deg=1 (self loop), cnt=0, out=0 ----------------
__global__ void k_init(float* __restrict__ deg, int* __restrict__ cnt,
                       float* __restrict__ out) {
    int i = blockIdx.x * blockDim.x + threadIdx.x;
    if (i < N_NODES) { deg[i] = 1.0f; cnt[i] = 0; }
    if (i < N_GRAPHS * D) out[i] = 0.0f;
}

// ---------------- degree + in-edge count ----------------
__global__ void k_count_deg(const int* __restrict__ dst, const float* __restrict__ ew,
                            float* __restrict__ deg, int* __restrict__ cnt) {
    int e = blockIdx.x * blockDim.x + threadIdx.x;
    if (e < N_EDGES) {
        int d = dst[e];
        atomicAdd(&deg[d], ew[e]);
        atomicAdd(&cnt[d], 1);
    }
}

// ---------------- dinv (fused) + exclusive scan of cnt -> rowptr ------------
__global__ void k_scan1(const int* __restrict__ cnt, int* __restrict__ partial,
                        int* __restrict__ bsums, float* __restrict__ deg) {
    int t = threadIdx.x, b = blockIdx.x, i = b * 256 + t;
    if (i < N_NODES) {            // fused dinv: deg -> rsqrt(deg)
        float d = deg[i];
        deg[i] = d > 0.f ? rsqrtf(d) : 0.f;
    }
    int v = (i < N_NODES) ? cnt[i] : 0;
    int incl = v;
    int lane = t & 63;
#pragma unroll
    for (int off = 1; off < 64; off <<= 1) {
        int u = __shfl_up(incl, off);
        if (lane >= off) incl += u;
    }
    __shared__ int wsum[4];
    int w = t >> 6;
    if (lane == 63) wsum[w] = incl;
    __syncthreads();
    int add = 0;
    for (int k = 0; k < w; ++k) add += wsum[k];
    incl += add;
    if (i < N_NODES) partial[i] = incl;
    if (t == 255) bsums[b] = incl;
}

__global__ void k_scan2(int* __restrict__ bsums) {
    __shared__ int s[512];
    int t = threadIdx.x;
    s[t] = (t < NBLK) ? bsums[t] : 0;
    __syncthreads();
    for (int off = 1; off < 512; off <<= 1) {
        int u = (t >= off) ? s[t - off] : 0;
        __syncthreads();
        s[t] += u;
        __syncthreads();
    }
    if (t < NBLK) bsums[t] = (t == 0) ? 0 : s[t - 1];  // exclusive
}

__global__ void k_scan3(const int* __restrict__ partial, const int* __restrict__ cnt,
                        const int* __restrict__ bsums, int* __restrict__ rowptr,
                        int* __restrict__ cursor) {
    int i = blockIdx.x * 256 + threadIdx.x;
    if (i < N_NODES) {
        int excl = partial[i] - cnt[i] + bsums[blockIdx.x];
        rowptr[i] = excl;
        cursor[i] = excl;
    }
}

// ---------------- scatter edges into CSR (src, norm) grouped by dst ----------
__global__ void k_scatter(const int* __restrict__ src, const int* __restrict__ dst,
                          const float* __restrict__ ew, const float* __restrict__ dinv,
                          int* __restrict__ cursor, float2* __restrict__ csr) {
    int e = blockIdx.x * blockDim.x + threadIdx.x;
    if (e < N_EDGES) {
        int s = src[e];
        int d = dst[e];
        float nrm = dinv[s] * ew[e] * dinv[d];
        int pos = atomicAdd(&cursor[d], 1);
        csr[pos] = make_float2(__int_as_float(s), nrm);   // low word = src bits
    }
}

// ---------------- slice x: [N][64] -> [8][N][8] ----------------
__global__ void k_slice(const float* __restrict__ x, float* __restrict__ xs) {
    int idx = blockIdx.x * blockDim.x + threadIdx.x;
    const int total = N_NODES * 64;
    const int stride = gridDim.x * blockDim.x;
    for (; idx < total; idx += stride) {
        int node = idx >> 6, c = idx & 63;
        xs[(c >> 3) * NS8 + node * 8 + (c & 7)] = x[idx];
    }
}

// ---------------- XCD-local sliced aggregation ----------------
// Block handles feature-slice s = blockIdx&7 (round-robin XCD pinning); the
// slice's 3.2 MB table is L2-resident on that XCD. 64 lanes = 8 edge-slots x
// 8 feats: ONE csr load + ONE gather instruction covers 8 edges. csr stream
// and agg output use nontemporal hints to protect the cached table.
__global__ __launch_bounds__(256) void k_agg(
        const float* __restrict__ tab_base,          // sliced in  [8][N][8]
        const long long* __restrict__ csr64,
        const float* __restrict__ dinv,
        const int* __restrict__ rowptr, const int* __restrict__ cnt,
        float* __restrict__ agg) {                   // std rows out [N][64]
    const int s    = blockIdx.x & 7;
    const int qb   = blockIdx.x >> 3;
    const int bps  = gridDim.x >> 3;                 // blocks per slice
    const float* __restrict__ tab = tab_base + (size_t)s * NS8;
    const int lane = threadIdx.x & 63;
    const int wid  = threadIdx.x >> 6;
    const int slot = lane >> 3;                      // 0..7 edge slot
    const int f    = lane & 7;                       // 0..7 feature
    const int wv   = qb * 4 + wid;
    const int tws  = bps * 4;

    for (int row = wv; row < N_NODES; row += tws) {
        const int st = rowptr[row];
        const int dg = cnt[row];
        const float di = dinv[row];
        float acc = (slot == 0) ? tab[row * 8 + f] * (di * di) : 0.f;  // self
        const int dgm1 = dg - 1;
        for (int j = 0; j < dg; j += 32) {
            int e0 = j + slot, e1 = j + 8 + slot, e2 = j + 16 + slot, e3 = j + 24 + slot;
            long long c0 = __builtin_nontemporal_load(&csr64[st + (e0 < dgm1 ? e0 : dgm1)]);
            long long c1 = __builtin_nontemporal_load(&csr64[st + (e1 < dgm1 ? e1 : dgm1)]);
            long long c2 = __builtin_nontemporal_load(&csr64[st + (e2 < dgm1 ? e2 : dgm1)]);
            long long c3 = __builtin_nontemporal_load(&csr64[st + (e3 < dgm1 ? e3 : dgm1)]);
            int   i0 = (int)(c0 & 0xffffffffLL);
            int   i1 = (int)(c1 & 0xffffffffLL);
            int   i2 = (int)(c2 & 0xffffffffLL);
            int   i3 = (int)(c3 & 0xffffffffLL);
            float w0 = (e0 < dg) ? __int_as_float((int)(c0 >> 32)) : 0.f;
            float w1 = (e1 < dg) ? __int_as_float((int)(c1 >> 32)) : 0.f;
            float w2 = (e2 < dg) ? __int_as_float((int)(c2 >> 32)) : 0.f;
            float w3 = (e3 < dg) ? __int_as_float((int)(c3 >> 32)) : 0.f;
            float v0 = tab[i0 * 8 + f];                // L2-local gathers
            float v1 = tab[i1 * 8 + f];
            float v2 = tab[i2 * 8 + f];
            float v3 = tab[i3 * 8 + f];
            acc = fmaf(v0, w0, acc);
            acc = fmaf(v1, w1, acc);
            acc = fmaf(v2, w2, acc);
            acc = fmaf(v3, w3, acc);
        }
        // reduce the 8 edge-slots per feature
        acc += __shfl_xor(acc, 8);
        acc += __shfl_xor(acc, 16);
        acc += __shfl_xor(acc, 32);
        if (lane < 8)
            __builtin_nontemporal_store(acc, &agg[(size_t)row * D + s * 8 + lane]);
    }
}

// ---------------- dense GEMM + bias + relu ----------------
// MODE 0: write result into sliced layout (next layer's gather table).
// MODE 1: pool-atomicAdd into out[batch[row]].
template <int MODE>
__global__ __launch_bounds__(256) void k_gemm(
        const float* __restrict__ inrows, const float* __restrict__ W,
        const float* __restrict__ bias, const int* __restrict__ batch,
        float* __restrict__ outp) {
    __shared__ float WTs[D * WTS];
    __shared__ float aw[4][D];
    __shared__ float bs[D];
    {   // stage W transposed: WTs[c*WTS + k] = W[k*D + c]
        int t = threadIdx.x;
#pragma unroll
        for (int i = 0; i < 16; ++i) {
            int idx = t + i * 256;
            int k = idx >> 6, c = idx & 63;
            WTs[c * WTS + k] = W[idx];
        }
        if (t < D) bs[t] = bias[t];
    }
    __syncthreads();

    const int lane = threadIdx.x & 63;
    const int wid  = threadIdx.x >> 6;
    float* awm = aw[wid];
    const float bl = bs[lane];

    int gw = (blockIdx.x * blockDim.x + threadIdx.x) >> 6;
    const int tw = (gridDim.x * blockDim.x) >> 6;

    for (int row = gw; row < N_NODES; row += tw) {
        awm[lane] = inrows[(size_t)row * D + lane];
        float r0 = 0.f, r1 = 0.f, r2 = 0.f, r3 = 0.f;
#pragma unroll
        for (int t = 0; t < 16; ++t) {
            float4 a = *(const float4*)&awm[t * 4];                // broadcast
            float4 w = *(const float4*)&WTs[lane * WTS + t * 4];   // conflict-free
            r0 = fmaf(a.x, w.x, r0);
            r1 = fmaf(a.y, w.y, r1);
            r2 = fmaf(a.z, w.z, r2);
            r3 = fmaf(a.w, w.w, r3);
        }
        float r = fmaxf((r0 + r1) + (r2 + r3) + bl, 0.f);
        if (MODE == 0) {
            outp[(lane >> 3) * NS8 + row * 8 + (lane & 7)] = r;   // sliced
        } else {
            atomicAdd(&outp[batch[row] * D + lane], r);
        }
    }
}

// ---------------- finalize pool: divide by per-graph node count ----------------
__global__ void k_finalize(float* __restrict__ out, const int* __restrict__ batch) {
    int g = blockIdx.x;
    int lane = threadIdx.x;
    int lo = 0, hi = N_NODES;
    while (lo < hi) { int m = (lo + hi) >> 1; if (batch[m] < g) lo = m + 1; else hi = m; }
    int start = lo;
    hi = N_NODES;
    while (lo < hi) { int m = (lo + hi) >> 1; if (batch[m] < g + 1) lo = m + 1; else hi = m; }
    float c = (float)(lo - start);
    out[g * D + lane] /= fmaxf(c, 1.0f);
}

// ---------------- fallback fused layer (round-7 proven path) ----------------
template <int LAYER>
__global__ __launch_bounds__(1024) void k_layer_fb(
        const float* __restrict__ in, const float* __restrict__ W,
        const float* __restrict__ bias, const float* __restrict__ dinv,
        const int* __restrict__ rowptr, const int* __restrict__ cnt,
        const float2* __restrict__ csr, const int* __restrict__ batch,
        float* __restrict__ outp) {
    __shared__ float WTs[D * WTS];
    __shared__ float aw[16][D];
    __shared__ float bs[D];
    {
        int t = threadIdx.x;
#pragma unroll
        for (int i = 0; i < 4; ++i) {
            int idx = t + i * 1024;
            int k = idx >> 6, c = idx & 63;
            WTs[c * WTS + k] = W[idx];
        }
        if (t < D) bs[t] = bias[t];
    }
    __syncthreads();
    const int lane = threadIdx.x & 63;
    const int wid  = threadIdx.x >> 6;
    float* awm = aw[wid];
    const float bl = bs[lane];
    int gw = (blockIdx.x * blockDim.x + threadIdx.x) >> 6;
    const int tw = (gridDim.x * blockDim.x) >> 6;
    for (int row = gw; row < N_NODES; row += tw) {
        const int st = __builtin_amdgcn_readfirstlane(rowptr[row]);
        const int dg = __builtin_amdgcn_readfirstlane(cnt[row]);
        const int dgm1 = dg - 1;
        float di = dinv[row];
        float acc = in[row * D + lane] * (di * di);
        const int passes = (dg + 7) >> 3;
        for (int p = 0; p < passes; ++p) {
            const int j = p * 8;
            float2 e0 = csr[st + (j + 0 < dgm1 ? j + 0 : dgm1)];
            float2 e1 = csr[st + (j + 1 < dgm1 ? j + 1 : dgm1)];
            float2 e2 = csr[st + (j + 2 < dgm1 ? j + 2 : dgm1)];
            float2 e3 = csr[st + (j + 3 < dgm1 ? j + 3 : dgm1)];
            float2 e4 = csr[st + (j + 4 < dgm1 ? j + 4 : dgm1)];
            float2 e5 = csr[st + (j + 5 < dgm1 ? j + 5 : dgm1)];
            float2 e6 = csr[st + (j + 6 < dgm1 ? j + 6 : dgm1)];
            float2 e7 = csr[st + (j + 7 < dgm1 ? j + 7 : dgm1)];
            float w0 = (j + 0 < dg) ? e0.y : 0.f;
            float w1 = (j + 1 < dg) ? e1.y : 0.f;
            float w2 = (j + 2 < dg) ? e2.y : 0.f;
            float w3 = (j + 3 < dg) ? e3.y : 0.f;
            float w4 = (j + 4 < dg) ? e4.y : 0.f;
            float w5 = (j + 5 < dg) ? e5.y : 0.f;
            float w6 = (j + 6 < dg) ? e6.y : 0.f;
            float w7 = (j + 7 < dg) ? e7.y : 0.f;
            int s0 = __builtin_amdgcn_readfirstlane(__float_as_int(e0.x));
            int s1 = __builtin_amdgcn_readfirstlane(__float_as_int(e1.x));
            int s2 = __builtin_amdgcn_readfirstlane(__float_as_int(e2.x));
            int s3 = __builtin_amdgcn_readfirstlane(__float_as_int(e3.x));
            int s4 = __builtin_amdgcn_readfirstlane(__float_as_int(e4.x));
            int s5 = __builtin_amdgcn_readfirstlane(__float_as_int(e5.x));
            int s6 = __builtin_amdgcn_readfirstlane(__float_as_int(e6.x));
            int s7 = __builtin_amdgcn_readfirstlane(__float_as_int(e7.x));
            float v0 = in[s0 * D + lane];
            float v1 = in[s1 * D + lane];
            float v2 = in[s2 * D + lane];
            float v3 = in[s3 * D + lane];
            float v4 = in[s4 * D + lane];
            float v5 = in[s5 * D + lane];
            float v6 = in[s6 * D + lane];
            float v7 = in[s7 * D + lane];
            acc = fmaf(v0, w0, acc); acc = fmaf(v1, w1, acc);
            acc = fmaf(v2, w2, acc); acc = fmaf(v3, w3, acc);
            acc = fmaf(v4, w4, acc); acc = fmaf(v5, w5, acc);
            acc = fmaf(v6, w6, acc); acc = fmaf(v7, w7, acc);
        }
        awm[lane] = acc;
        float r0 = 0.f, r1 = 0.f, r2 = 0.f, r3 = 0.f;
#pragma unroll
        for (int t = 0; t < 16; ++t) {
            float4 a = *(const float4*)&awm[t * 4];
            float4 w = *(const float4*)&WTs[lane * WTS + t * 4];
            r0 = fmaf(a.x, w.x, r0);
            r1 = fmaf(a.y, w.y, r1);
            r2 = fmaf(a.z, w.z, r2);
            r3 = fmaf(a.w, w.w, r3);
        }
        float r = fmaxf((r0 + r1) + (r2 + r3) + bl, 0.f);
        if (LAYER == 1) outp[row * D + lane] = r;
        else atomicAdd(&outp[batch[row] * D + lane], r);
    }
}

// ---------------- launch ----------------
extern "C" void kernel_launch(void* const* d_in, const int* in_sizes, int n_in,
                              void* d_out, int out_size, void* d_ws, size_t ws_size,
                              hipStream_t stream) {
    const float* x     = (const float*)d_in[0];
    const int*   ei    = (const int*)d_in[1];
    const int*   src   = ei;
    const int*   dst   = ei + N_EDGES;
    const int*   batch = (const int*)d_in[2];
    const float* ew    = (const float*)d_in[3];
    const float* W1    = (const float*)d_in[4];
    const float* b1    = (const float*)d_in[5];
    const float* W2    = (const float*)d_in[6];
    const float* b2    = (const float*)d_in[7];
    float* out = (float*)d_out;
    char* ws = (char*)d_ws;

    if (ws_size >= 65700000) {
        // -------- feature-sliced XCD-local path --------
        float*  xs     = (float*)(ws);                    // 25.6 MB sliced x / h
        float*  agg    = (float*)(ws + 25600000);         // 25.6 MB std-row agg
        float2* csr    = (float2*)(ws + 51200000);        // 12.8 MB
        float*  deg    = (float*)(ws + 64000000);
        int*    cnt    = (int*)(ws + 64400000);
        int*    rowptr = (int*)(ws + 64800000);
        int*    cursor = (int*)(ws + 65200000);
        int*    bsums  = (int*)(ws + 65600000);
        const long long* csr64 = (const long long*)csr;

        k_init<<<NBLK, 256, 0, stream>>>(deg, cnt, out);
        k_count_deg<<<(N_EDGES + 255) / 256, 256, 0, stream>>>(dst, ew, deg, cnt);
        k_scan1<<<NBLK, 256, 0, stream>>>(cnt, rowptr, bsums, deg);
        k_scan2<<<1, 512, 0, stream>>>(bsums);
        k_scan3<<<NBLK, 256, 0, stream>>>(rowptr, cnt, bsums, rowptr, cursor);
        k_scatter<<<(N_EDGES + 255) / 256, 256, 0, stream>>>(src, dst, ew, deg, cursor, csr);

        k_slice<<<4096, 256, 0, stream>>>(x, xs);
        // layer 1
        k_agg<<<4096, 256, 0, stream>>>(xs, csr64, deg, rowptr, cnt, agg);
        k_gemm<0><<<2048, 256, 0, stream>>>(agg, W1, b1, batch, xs);   // h1 sliced
        // layer 2 + pool
        k_agg<<<4096, 256, 0, stream>>>(xs, csr64, deg, rowptr, cnt, agg);
        k_gemm<1><<<2048, 256, 0, stream>>>(agg, W2, b2, batch, out);
        k_finalize<<<N_GRAPHS, D, 0, stream>>>(out, batch);
    } else {
        // -------- fallback: round-7 proven path --------
        float*  bufA   = (float*)(ws);
        float2* csr    = (float2*)(ws + 25600000);
        float*  deg    = (float*)(ws + 38400000);
        int*    cnt    = (int*)(ws + 38800000);
        int*    rowptr = (int*)(ws + 39200000);
        int*    cursor = (int*)(ws + 39600000);
        int*    bsums  = (int*)(ws + 40000000);

        k_init<<<NBLK, 256, 0, stream>>>(deg, cnt, out);
        k_count_deg<<<(N_EDGES + 255) / 256, 256, 0, stream>>>(dst, ew, deg, cnt);
        k_scan1<<<NBLK, 256, 0, stream>>>(cnt, rowptr, bsums, deg);
        k_scan2<<<1, 512, 0, stream>>>(bsums);
        k_scan3<<<NBLK, 256, 0, stream>>>(rowptr, cnt, bsums, rowptr, cursor);
        k_scatter<<<(N_EDGES + 255) / 256, 256, 0, stream>>>(src, dst, ew, deg, cursor, csr);
        k_layer_fb<1><<<512, 1024, 0, stream>>>(x, W1, b1, deg, rowptr, cnt, csr, batch, bufA);
        k_layer_fb<2><<<512, 1024, 0, stream>>>(bufA, W2, b2, deg, rowptr, cnt, csr, batch, out);
        k_finalize<<<N_GRAPHS, D, 0, stream>>>(out, batch);
    }
}

// Round 12
// 508.066 us; speedup vs baseline: 1.5715x; 1.5715x over previous
//
#include <hip/hip_runtime.h>

#define N_NODES 100000
#define N_EDGES 1600000
#define D 64
#define N_GRAPHS 64
#define NBLK ((N_NODES + 255) / 256)   // 391 scan blocks
#define WTS 68                         // WT row stride (floats): conflict-free

// ---------------- degree + in-edge count (deg starts at 0 via memset) -------
__global__ void k_count_deg(const int* __restrict__ dst, const float* __restrict__ ew,
                            float* __restrict__ deg, int* __restrict__ cnt) {
    int e = blockIdx.x * blockDim.x + threadIdx.x;
    if (e < N_EDGES) {
        int d = dst[e];
        atomicAdd(&deg[d], ew[e]);
        atomicAdd(&cnt[d], 1);
    }
}

// ---------------- dinv (fused, +1 self-loop) + scan of cnt ------------------
__global__ void k_scan1(const int* __restrict__ cnt, int* __restrict__ partial,
                        int* __restrict__ bsums, float* __restrict__ deg) {
    int t = threadIdx.x, b = blockIdx.x, i = b * 256 + t;
    if (i < N_NODES) {
        float d = deg[i];
        deg[i] = rsqrtf(d + 1.0f);    // self-loop weight 1 => always > 0
    }
    int v = (i < N_NODES) ? cnt[i] : 0;
    int incl = v;
    int lane = t & 63;
#pragma unroll
    for (int off = 1; off < 64; off <<= 1) {
        int u = __shfl_up(incl, off);
        if (lane >= off) incl += u;
    }
    __shared__ int wsum[4];
    int w = t >> 6;
    if (lane == 63) wsum[w] = incl;
    __syncthreads();
    int add = 0;
    for (int k = 0; k < w; ++k) add += wsum[k];
    incl += add;
    if (i < N_NODES) partial[i] = incl;
    if (t == 255) bsums[b] = incl;
}

__global__ void k_scan2(int* __restrict__ bsums) {
    __shared__ int s[512];
    int t = threadIdx.x;
    s[t] = (t < NBLK) ? bsums[t] : 0;
    __syncthreads();
    for (int off = 1; off < 512; off <<= 1) {
        int u = (t >= off) ? s[t - off] : 0;
        __syncthreads();
        s[t] += u;
        __syncthreads();
    }
    if (t < NBLK) bsums[t] = (t == 0) ? 0 : s[t - 1];  // exclusive
}

__global__ void k_scan3(const int* __restrict__ partial, const int* __restrict__ cnt,
                        const int* __restrict__ bsums, int* __restrict__ rowptr,
                        int* __restrict__ cursor) {
    int i = blockIdx.x * 256 + threadIdx.x;
    if (i < N_NODES) {
        int excl = partial[i] - cnt[i] + bsums[blockIdx.x];
        rowptr[i] = excl;
        cursor[i] = excl;
    }
}

// ---------------- scatter edges into CSR (src, norm) grouped by dst ----------
__global__ void k_scatter(const int* __restrict__ src, const int* __restrict__ dst,
                          const float* __restrict__ ew, const float* __restrict__ dinv,
                          int* __restrict__ cursor, float2* __restrict__ csr) {
    int e = blockIdx.x * blockDim.x + threadIdx.x;
    if (e < N_EDGES) {
        int s = src[e];
        int d = dst[e];
        float nrm = dinv[s] * ew[e] * dinv[d];
        int pos = atomicAdd(&cursor[d], 1);
        csr[pos] = make_float2(__int_as_float(s), nrm);
    }
}

// ---------------- fused layer, float4-grouped gathers ----------------
// One row per wave-iteration. lane = (slot in [0,4)) * 16 + (q in [0,16)).
// Per 16-edge pass: ONE per-lane csr load (16 edges), 8 shfl to distribute
// (src,w) to slots, then FOUR float4-gather instructions (each covers 4
// edges, 1 KB) -> 4x fewer vmem instructions for the same bytes in flight.
// Row reduce: 8 shfl_xor folds slots; lanes 0..15 write the row to LDS.
// GEMM: lane's W-column from transposed-W LDS (stride 68, conflict-free),
// acc broadcast via float4 reads. LAYER==1: write relu(.); LAYER==2:
// pool-atomicAdd relu(.) into out[batch].
template <int LAYER>
__global__ __launch_bounds__(256) void k_layer(
        const float* __restrict__ in, const float* __restrict__ W,
        const float* __restrict__ bias, const float* __restrict__ dinv,
        const int* __restrict__ rowptr, const int* __restrict__ cnt,
        const float2* __restrict__ csr, const int* __restrict__ batch,
        float* __restrict__ outp) {
    __shared__ float WTs[D * WTS];       // 17408 B transposed W
    __shared__ float aw[4][D];           // per-wave row staging
    __shared__ float bs[D];

    {   // stage W transposed: WTs[c*WTS + k] = W[k*D + c]
        int t = threadIdx.x;
#pragma unroll
        for (int i = 0; i < 16; ++i) {
            int idx = t + i * 256;
            int k = idx >> 6, c = idx & 63;
            WTs[c * WTS + k] = W[idx];
        }
        if (t < D) bs[t] = bias[t];
    }
    __syncthreads();

    const int lane = threadIdx.x & 63;
    const int wid  = threadIdx.x >> 6;
    const int slot = lane >> 4;          // 0..3
    const int q    = lane & 15;          // 0..15
    float* awm = aw[wid];
    const float bl = bs[lane];
    const float4* in4 = (const float4*)in;

    int gw = (blockIdx.x * blockDim.x + threadIdx.x) >> 6;
    const int tw = (gridDim.x * blockDim.x) >> 6;

    for (int row = gw; row < N_NODES; row += tw) {
        const int st = __builtin_amdgcn_readfirstlane(rowptr[row]);
        const int dg = __builtin_amdgcn_readfirstlane(cnt[row]);
        const int dgm1 = dg - 1;

        float4 acc = make_float4(0.f, 0.f, 0.f, 0.f);
        {   // self-loop on slot 0
            float di = dinv[row];
            if (slot == 0) {
                float4 s4 = in4[row * 16 + q];
                float d2 = di * di;
                acc.x = s4.x * d2; acc.y = s4.y * d2;
                acc.z = s4.z * d2; acc.w = s4.w * d2;
            }
        }

        for (int j = 0; j < dg; j += 16) {
            // per-lane csr load: lane (slot,q) fetches edge j+q (4x redundant)
            int ie = j + q;
            float2 c = csr[st + (ie < dgm1 ? ie : dgm1)];
            // distribute: slot handles sub-edges j+4k+slot, entry in lane 4k+slot
            float sx0 = __shfl(c.x, 4 * 0 + slot);
            float wv0 = __shfl(c.y, 4 * 0 + slot);
            float sx1 = __shfl(c.x, 4 * 1 + slot);
            float wv1 = __shfl(c.y, 4 * 1 + slot);
            float sx2 = __shfl(c.x, 4 * 2 + slot);
            float wv2 = __shfl(c.y, 4 * 2 + slot);
            float sx3 = __shfl(c.x, 4 * 3 + slot);
            float wv3 = __shfl(c.y, 4 * 3 + slot);
            wv0 = (j + 0 + slot  < dg) ? wv0 : 0.f;
            wv1 = (j + 4 + slot  < dg) ? wv1 : 0.f;
            wv2 = (j + 8 + slot  < dg) ? wv2 : 0.f;
            wv3 = (j + 12 + slot < dg) ? wv3 : 0.f;
            int i0 = __float_as_int(sx0);
            int i1 = __float_as_int(sx1);
            int i2 = __float_as_int(sx2);
            int i3 = __float_as_int(sx3);
            // 4 float4 gathers: each instruction covers 4 edges (1 KB)
            float4 v0 = in4[i0 * 16 + q];
            float4 v1 = in4[i1 * 16 + q];
            float4 v2 = in4[i2 * 16 + q];
            float4 v3 = in4[i3 * 16 + q];
            acc.x = fmaf(v0.x, wv0, acc.x); acc.y = fmaf(v0.y, wv0, acc.y);
            acc.z = fmaf(v0.z, wv0, acc.z); acc.w = fmaf(v0.w, wv0, acc.w);
            acc.x = fmaf(v1.x, wv1, acc.x); acc.y = fmaf(v1.y, wv1, acc.y);
            acc.z = fmaf(v1.z, wv1, acc.z); acc.w = fmaf(v1.w, wv1, acc.w);
            acc.x = fmaf(v2.x, wv2, acc.x); acc.y = fmaf(v2.y, wv2, acc.y);
            acc.z = fmaf(v2.z, wv2, acc.z); acc.w = fmaf(v2.w, wv2, acc.w);
            acc.x = fmaf(v3.x, wv3, acc.x); acc.y = fmaf(v3.y, wv3, acc.y);
            acc.z = fmaf(v3.z, wv3, acc.z); acc.w = fmaf(v3.w, wv3, acc.w);
        }

        // fold the 4 slots (same q): lanes 0..15 end with the row
        acc.x += __shfl_xor(acc.x, 16); acc.y += __shfl_xor(acc.y, 16);
        acc.z += __shfl_xor(acc.z, 16); acc.w += __shfl_xor(acc.w, 16);
        acc.x += __shfl_xor(acc.x, 32); acc.y += __shfl_xor(acc.y, 32);
        acc.z += __shfl_xor(acc.z, 32); acc.w += __shfl_xor(acc.w, 32);
        if (slot == 0) *(float4*)&awm[q * 4] = acc;
        // same-wave LDS RAW: in-order LDS pipe, no barrier needed

        // ---- GEMM: r[lane] = sum_k aw[k] * W[k][lane] ----
        float r0 = 0.f, r1 = 0.f, r2 = 0.f, r3 = 0.f;
#pragma unroll
        for (int t = 0; t < 16; ++t) {
            float4 a = *(const float4*)&awm[t * 4];                // broadcast
            float4 w = *(const float4*)&WTs[lane * WTS + t * 4];   // conflict-free
            r0 = fmaf(a.x, w.x, r0);
            r1 = fmaf(a.y, w.y, r1);
            r2 = fmaf(a.z, w.z, r2);
            r3 = fmaf(a.w, w.w, r3);
        }
        float r = fmaxf((r0 + r1) + (r2 + r3) + bl, 0.f);

        if (LAYER == 1) {
            outp[row * D + lane] = r;
        } else {
            atomicAdd(&outp[batch[row] * D + lane], r);
        }
    }
}

// ---------------- finalize pool: divide by per-graph node count ----------------
__global__ void k_finalize(float* __restrict__ out, const int* __restrict__ batch) {
    int g = blockIdx.x;
    int lane = threadIdx.x;
    int lo = 0, hi = N_NODES;
    while (lo < hi) { int m = (lo + hi) >> 1; if (batch[m] < g) lo = m + 1; else hi = m; }
    int start = lo;
    hi = N_NODES;
    while (lo < hi) { int m = (lo + hi) >> 1; if (batch[m] < g + 1) lo = m + 1; else hi = m; }
    float c = (float)(lo - start);
    out[g * D + lane] /= fmaxf(c, 1.0f);
}

// ---------------- launch ----------------
extern "C" void kernel_launch(void* const* d_in, const int* in_sizes, int n_in,
                              void* d_out, int out_size, void* d_ws, size_t ws_size,
                              hipStream_t stream) {
    const float* x     = (const float*)d_in[0];
    const int*   ei    = (const int*)d_in[1];
    const int*   src   = ei;
    const int*   dst   = ei + N_EDGES;
    const int*   batch = (const int*)d_in[2];
    const float* ew    = (const float*)d_in[3];
    const float* W1    = (const float*)d_in[4];
    const float* b1    = (const float*)d_in[5];
    const float* W2    = (const float*)d_in[6];
    const float* b2    = (const float*)d_in[7];
    float* out = (float*)d_out;

    char* ws = (char*)d_ws;
    float*  bufA   = (float*)(ws);                    // 25.6 MB  h1
    float2* csr    = (float2*)(ws + 25600000);        // 12.8 MB  (src, norm)
    float*  deg    = (float*)(ws + 38400000);         // 400 KB   deg -> dinv
    int*    cnt    = (int*)(ws + 38800000);           // 400 KB
    int*    rowptr = (int*)(ws + 39200000);           // 400 KB
    int*    cursor = (int*)(ws + 39600000);           // 400 KB
    int*    bsums  = (int*)(ws + 40000000);           // 2 KB

    // zero-init via async memset (deg accumulates from 0; dinv adds self-loop)
    hipMemsetAsync(deg, 0, N_NODES * sizeof(float), stream);
    hipMemsetAsync(cnt, 0, N_NODES * sizeof(int), stream);
    hipMemsetAsync(out, 0, N_GRAPHS * D * sizeof(float), stream);

    // normalization + CSR build
    k_count_deg<<<(N_EDGES + 255) / 256, 256, 0, stream>>>(dst, ew, deg, cnt);
    k_scan1<<<NBLK, 256, 0, stream>>>(cnt, rowptr, bsums, deg);   // + fused dinv
    k_scan2<<<1, 512, 0, stream>>>(bsums);
    k_scan3<<<NBLK, 256, 0, stream>>>(rowptr, cnt, bsums, rowptr, cursor);
    k_scatter<<<(N_EDGES + 255) / 256, 256, 0, stream>>>(src, dst, ew, deg, cursor, csr);

    // layer 1: bufA = relu((A x) W1 + b1)
    k_layer<1><<<2048, 256, 0, stream>>>(x, W1, b1, deg, rowptr, cnt, csr, batch, bufA);
    // layer 2 + pool-sum: out[g] += relu((A bufA) W2 + b2)
    k_layer<2><<<2048, 256, 0, stream>>>(bufA, W2, b2, deg, rowptr, cnt, csr, batch, out);
    // mean
    k_finalize<<<N_GRAPHS, D, 0, stream>>>(out, batch);
}

// Round 13
// 466.636 us; speedup vs baseline: 1.7111x; 1.0888x over previous
//
#include <hip/hip_runtime.h>
#include <hip/hip_fp16.h>

#define N_NODES 100000
#define N_EDGES 1600000
#define D 64
#define N_GRAPHS 64
#define NBLK ((N_NODES + 255) / 256)   // 391 scan blocks
#define WTS 68                         // WT row stride (floats): conflict-free

// ---------------- degree + in-edge count (deg starts at 0 via memset) -------
__global__ void k_count_deg(const int* __restrict__ dst, const float* __restrict__ ew,
                            float* __restrict__ deg, int* __restrict__ cnt) {
    int e = blockIdx.x * blockDim.x + threadIdx.x;
    if (e < N_EDGES) {
        int d = dst[e];
        atomicAdd(&deg[d], ew[e]);
        atomicAdd(&cnt[d], 1);
    }
}

// ---------------- dinv (fused, +1 self-loop) + scan of cnt ------------------
__global__ void k_scan1(const int* __restrict__ cnt, int* __restrict__ partial,
                        int* __restrict__ bsums, float* __restrict__ deg) {
    int t = threadIdx.x, b = blockIdx.x, i = b * 256 + t;
    if (i < N_NODES) {
        float d = deg[i];
        deg[i] = rsqrtf(d + 1.0f);    // self-loop weight 1 => always > 0
    }
    int v = (i < N_NODES) ? cnt[i] : 0;
    int incl = v;
    int lane = t & 63;
#pragma unroll
    for (int off = 1; off < 64; off <<= 1) {
        int u = __shfl_up(incl, off);
        if (lane >= off) incl += u;
    }
    __shared__ int wsum[4];
    int w = t >> 6;
    if (lane == 63) wsum[w] = incl;
    __syncthreads();
    int add = 0;
    for (int k = 0; k < w; ++k) add += wsum[k];
    incl += add;
    if (i < N_NODES) partial[i] = incl;
    if (t == 255) bsums[b] = incl;
}

__global__ void k_scan2(int* __restrict__ bsums) {
    __shared__ int s[512];
    int t = threadIdx.x;
    s[t] = (t < NBLK) ? bsums[t] : 0;
    __syncthreads();
    for (int off = 1; off < 512; off <<= 1) {
        int u = (t >= off) ? s[t - off] : 0;
        __syncthreads();
        s[t] += u;
        __syncthreads();
    }
    if (t < NBLK) bsums[t] = (t == 0) ? 0 : s[t - 1];  // exclusive
}

__global__ void k_scan3(const int* __restrict__ partial, const int* __restrict__ cnt,
                        const int* __restrict__ bsums, int* __restrict__ rowptr,
                        int* __restrict__ cursor) {
    int i = blockIdx.x * 256 + threadIdx.x;
    if (i < N_NODES) {
        int excl = partial[i] - cnt[i] + bsums[blockIdx.x];
        rowptr[i] = excl;
        cursor[i] = excl;
    }
}

// ---------------- scatter edges into CSR (src, norm) grouped by dst ----------
__global__ void k_scatter(const int* __restrict__ src, const int* __restrict__ dst,
                          const float* __restrict__ ew, const float* __restrict__ dinv,
                          int* __restrict__ cursor, float2* __restrict__ csr) {
    int e = blockIdx.x * blockDim.x + threadIdx.x;
    if (e < N_EDGES) {
        int s = src[e];
        int d = dst[e];
        float nrm = dinv[s] * ew[e] * dinv[d];
        int pos = atomicAdd(&cursor[d], 1);
        csr[pos] = make_float2(__int_as_float(s), nrm);
    }
}

// ---------------- x -> fp16 table ----------------
__global__ void k_half(const float* __restrict__ x, __half* __restrict__ xh) {
    int i = blockIdx.x * blockDim.x + threadIdx.x;
    const int total = N_NODES * D / 4;
    const int stride = gridDim.x * blockDim.x;
    const float4* x4 = (const float4*)x;
    __half2* xh2 = (__half2*)xh;
    for (; i < total; i += stride) {
        float4 v = x4[i];
        xh2[2 * i + 0] = __floats2half2_rn(v.x, v.y);
        xh2[2 * i + 1] = __floats2half2_rn(v.z, v.w);
    }
}

// ---------------- fused layer (fp16 gather table) ----------------
// One row per wave-iteration (r7 structure, unchanged shape). Gather table is
// fp16: each edge-row read is 128 B instead of 256 B -> halves the per-XCD
// L2-miss traffic that seven structural variants proved to be the wall.
// Fully-predicated unroll-8 passes (clamped index, zeroed weight).
// GEMM: f32, lane's W-column from transposed-W LDS (stride 68, conflict-free),
// acc broadcast via 1 ds_write + same-address float4 reads.
// LAYER==1: write relu(.) as fp16 into outh.  LAYER==2: f32 pool-atomicAdd.
template <int LAYER>
__global__ __launch_bounds__(1024) void k_layer(
        const __half* __restrict__ in, const float* __restrict__ W,
        const float* __restrict__ bias, const float* __restrict__ dinv,
        const int* __restrict__ rowptr, const int* __restrict__ cnt,
        const float2* __restrict__ csr, const int* __restrict__ batch,
        __half* __restrict__ outh, float* __restrict__ outf) {
    __shared__ float WTs[D * WTS];       // 17408 B transposed W
    __shared__ float aw[16][D];          // 4 KB per-wave row staging
    __shared__ float bs[D];

    {   // stage W transposed: WTs[c*WTS + k] = W[k*D + c]
        int t = threadIdx.x;
#pragma unroll
        for (int i = 0; i < 4; ++i) {
            int idx = t + i * 1024;
            int k = idx >> 6, c = idx & 63;
            WTs[c * WTS + k] = W[idx];
        }
        if (t < D) bs[t] = bias[t];
    }
    __syncthreads();

    const int lane = threadIdx.x & 63;
    const int wid  = threadIdx.x >> 6;
    float* awm = aw[wid];
    const float bl = bs[lane];

    int gw = (blockIdx.x * blockDim.x + threadIdx.x) >> 6;
    const int tw = (gridDim.x * blockDim.x) >> 6;

    for (int row = gw; row < N_NODES; row += tw) {
        const int st = __builtin_amdgcn_readfirstlane(rowptr[row]);
        const int dg = __builtin_amdgcn_readfirstlane(cnt[row]);
        const int dgm1 = dg - 1;
        float di = dinv[row];
        float acc = __half2float(in[row * D + lane]) * (di * di);   // self-loop

        const int passes = (dg + 7) >> 3;
        for (int p = 0; p < passes; ++p) {
            const int j = p * 8;
            int  jj0 = j + 0, jj1 = j + 1, jj2 = j + 2, jj3 = j + 3;
            int  jj4 = j + 4, jj5 = j + 5, jj6 = j + 6, jj7 = j + 7;
            float2 e0 = csr[st + (jj0 < dgm1 ? jj0 : dgm1)];
            float2 e1 = csr[st + (jj1 < dgm1 ? jj1 : dgm1)];
            float2 e2 = csr[st + (jj2 < dgm1 ? jj2 : dgm1)];
            float2 e3 = csr[st + (jj3 < dgm1 ? jj3 : dgm1)];
            float2 e4 = csr[st + (jj4 < dgm1 ? jj4 : dgm1)];
            float2 e5 = csr[st + (jj5 < dgm1 ? jj5 : dgm1)];
            float2 e6 = csr[st + (jj6 < dgm1 ? jj6 : dgm1)];
            float2 e7 = csr[st + (jj7 < dgm1 ? jj7 : dgm1)];
            float w0 = (jj0 < dg) ? e0.y : 0.f;
            float w1 = (jj1 < dg) ? e1.y : 0.f;
            float w2 = (jj2 < dg) ? e2.y : 0.f;
            float w3 = (jj3 < dg) ? e3.y : 0.f;
            float w4 = (jj4 < dg) ? e4.y : 0.f;
            float w5 = (jj5 < dg) ? e5.y : 0.f;
            float w6 = (jj6 < dg) ? e6.y : 0.f;
            float w7 = (jj7 < dg) ? e7.y : 0.f;
            int s0 = __builtin_amdgcn_readfirstlane(__float_as_int(e0.x));
            int s1 = __builtin_amdgcn_readfirstlane(__float_as_int(e1.x));
            int s2 = __builtin_amdgcn_readfirstlane(__float_as_int(e2.x));
            int s3 = __builtin_amdgcn_readfirstlane(__float_as_int(e3.x));
            int s4 = __builtin_amdgcn_readfirstlane(__float_as_int(e4.x));
            int s5 = __builtin_amdgcn_readfirstlane(__float_as_int(e5.x));
            int s6 = __builtin_amdgcn_readfirstlane(__float_as_int(e6.x));
            int s7 = __builtin_amdgcn_readfirstlane(__float_as_int(e7.x));
            float v0 = __half2float(in[s0 * D + lane]);   // 128 B / edge
            float v1 = __half2float(in[s1 * D + lane]);
            float v2 = __half2float(in[s2 * D + lane]);
            float v3 = __half2float(in[s3 * D + lane]);
            float v4 = __half2float(in[s4 * D + lane]);
            float v5 = __half2float(in[s5 * D + lane]);
            float v6 = __half2float(in[s6 * D + lane]);
            float v7 = __half2float(in[s7 * D + lane]);
            acc = fmaf(v0, w0, acc);
            acc = fmaf(v1, w1, acc);
            acc = fmaf(v2, w2, acc);
            acc = fmaf(v3, w3, acc);
            acc = fmaf(v4, w4, acc);
            acc = fmaf(v5, w5, acc);
            acc = fmaf(v6, w6, acc);
            acc = fmaf(v7, w7, acc);
        }

        // ---- GEMM: r[lane] = sum_k acc[k] * W[k][lane] ----
        awm[lane] = acc;   // same-wave LDS RAW; compiler inserts lgkmcnt wait
        float r0 = 0.f, r1 = 0.f, r2 = 0.f, r3 = 0.f;
#pragma unroll
        for (int t = 0; t < 16; ++t) {
            float4 a = *(const float4*)&awm[t * 4];                // broadcast
            float4 w = *(const float4*)&WTs[lane * WTS + t * 4];   // conflict-free
            r0 = fmaf(a.x, w.x, r0);
            r1 = fmaf(a.y, w.y, r1);
            r2 = fmaf(a.z, w.z, r2);
            r3 = fmaf(a.w, w.w, r3);
        }
        float r = fmaxf((r0 + r1) + (r2 + r3) + bl, 0.f);

        if (LAYER == 1) {
            outh[row * D + lane] = __float2half_rn(r);   // fp16 table for L2
        } else {
            atomicAdd(&outf[batch[row] * D + lane], r);
        }
    }
}

// ---------------- finalize pool: divide by per-graph node count ----------------
__global__ void k_finalize(float* __restrict__ out, const int* __restrict__ batch) {
    int g = blockIdx.x;
    int lane = threadIdx.x;
    int lo = 0, hi = N_NODES;
    while (lo < hi) { int m = (lo + hi) >> 1; if (batch[m] < g) lo = m + 1; else hi = m; }
    int start = lo;
    hi = N_NODES;
    while (lo < hi) { int m = (lo + hi) >> 1; if (batch[m] < g + 1) lo = m + 1; else hi = m; }
    float c = (float)(lo - start);
    out[g * D + lane] /= fmaxf(c, 1.0f);
}

// ---------------- launch ----------------
extern "C" void kernel_launch(void* const* d_in, const int* in_sizes, int n_in,
                              void* d_out, int out_size, void* d_ws, size_t ws_size,
                              hipStream_t stream) {
    const float* x     = (const float*)d_in[0];
    const int*   ei    = (const int*)d_in[1];
    const int*   src   = ei;
    const int*   dst   = ei + N_EDGES;
    const int*   batch = (const int*)d_in[2];
    const float* ew    = (const float*)d_in[3];
    const float* W1    = (const float*)d_in[4];
    const float* b1    = (const float*)d_in[5];
    const float* W2    = (const float*)d_in[6];
    const float* b2    = (const float*)d_in[7];
    float* out = (float*)d_out;

    char* ws = (char*)d_ws;
    __half* xh     = (__half*)(ws);                   // 12.8 MB fp16 x
    __half* hh     = (__half*)(ws + 12800000);        // 12.8 MB fp16 h1
    float2* csr    = (float2*)(ws + 25600000);        // 12.8 MB (src, norm)
    float*  deg    = (float*)(ws + 38400000);         // 400 KB  deg -> dinv
    int*    cnt    = (int*)(ws + 38800000);           // 400 KB
    int*    rowptr = (int*)(ws + 39200000);           // 400 KB
    int*    cursor = (int*)(ws + 39600000);           // 400 KB
    int*    bsums  = (int*)(ws + 40000000);           // 2 KB

    // zero-init via async memset (deg accumulates from 0; dinv adds self-loop)
    hipMemsetAsync(deg, 0, N_NODES * sizeof(float), stream);
    hipMemsetAsync(cnt, 0, N_NODES * sizeof(int), stream);
    hipMemsetAsync(out, 0, N_GRAPHS * D * sizeof(float), stream);

    // normalization + CSR build (+ fp16 conversion of x, independent)
    k_half<<<1024, 256, 0, stream>>>(x, xh);
    k_count_deg<<<(N_EDGES + 255) / 256, 256, 0, stream>>>(dst, ew, deg, cnt);
    k_scan1<<<NBLK, 256, 0, stream>>>(cnt, rowptr, bsums, deg);   // + fused dinv
    k_scan2<<<1, 512, 0, stream>>>(bsums);
    k_scan3<<<NBLK, 256, 0, stream>>>(rowptr, cnt, bsums, rowptr, cursor);
    k_scatter<<<(N_EDGES + 255) / 256, 256, 0, stream>>>(src, dst, ew, deg, cursor, csr);

    // layer 1: hh = fp16(relu((A xh) W1 + b1))
    k_layer<1><<<512, 1024, 0, stream>>>(xh, W1, b1, deg, rowptr, cnt, csr, batch, hh, out);
    // layer 2 + pool-sum: out[g] += relu((A hh) W2 + b2)
    k_layer<2><<<512, 1024, 0, stream>>>(hh, W2, b2, deg, rowptr, cnt, csr, batch, hh, out);
    // mean
    k_finalize<<<N_GRAPHS, D, 0, stream>>>(out, batch);
}